// Round 7
// baseline (155.486 us; speedup 1.0000x reference)
//
#include <hip/hip_runtime.h>
#include <hip/hip_bf16.h>

#define N_NODES 100000
#define IN_DIM  128
#define HIDDEN  64
#define N_EDGES 1600000

typedef unsigned short u16;
typedef unsigned int   u32;
typedef unsigned char  u8;

typedef __attribute__((ext_vector_type(8))) short bf16x8;  // 8 bf16 in 4 VGPRs
typedef __attribute__((ext_vector_type(4))) float f32x4;
typedef __attribute__((ext_vector_type(2))) float f32x2;

__device__ __forceinline__ u16 f2bf(float f) {
    // round-to-nearest-even fp32 -> bf16
    u32 u = __float_as_uint(f);
    u32 r = 0x7FFFu + ((u >> 16) & 1u);
    u += r;
    return (u16)(u >> 16);
}

__device__ __forceinline__ u8 f2fp8(float f) {
    // fp32 -> OCP e4m3 via HW cvt (RNE, satfinite)
    u32 p = (u32)__builtin_amdgcn_cvt_pk_fp8_f32(f, f, 0, false);
    return (u8)(p & 0xFF);
}

// ---------------------------------------------------------------------------
// Kernel 1: persistent grid-stride GEMM (bf16 MFMA) with W-staging FUSED:
// each block converts W1 (fp32 [256][64], L2/L3-resident) directly into its
// LDS B-tile Bs[jj][k] = Wcat[k][jj], coalesced over jj. Epilogue quantizes
// pre-activations to fp8 e4m3: UVq[node][128] B, U=cols 0..63, V=64..127.
// ---------------------------------------------------------------------------
#define LDK 136   // 128 + 8 bf16 pad -> row stride 272 B (16B-aligned)
#define GEMM_BLOCKS 625

__global__ __launch_bounds__(256) void gemm_kernel(const float* __restrict__ z,
                                                   const float* __restrict__ W1,
                                                   const float* __restrict__ b1,
                                                   u8* __restrict__ UVq) {
    __shared__ u16 Bs[128 * LDK];   // 128 x 136 bf16 (34.8 KB)

    int tid = threadIdx.x;
    // Stage Wcat from W1: lanes walk jj (contiguous fp32) -> coalesced reads.
    // Bs[jj][k]    = W1[k][jj]          (U half)
    // Bs[64+jj][k] = W1[128+k][jj]      (V half)
    for (int cIdx = tid; cIdx < 8192; cIdx += 256) {
        int k  = cIdx >> 6;
        int jj = cIdx & 63;
        Bs[jj * LDK + k]        = f2bf(W1[k * 64 + jj]);
        Bs[(64 + jj) * LDK + k] = f2bf(W1[(128 + k) * 64 + jj]);
    }
    __syncthreads();

    int wave = tid >> 6;
    int lane = tid & 63;
    int quad = lane >> 4;
    int l16  = lane & 15;

    int gwid   = blockIdx.x * 4 + wave;
    int nwaves = GEMM_BLOCKS * 4;
    const int NTILES = N_NODES / 16;   // 6250

    float bias[4];
#pragma unroll
    for (int nt = 0; nt < 4; nt++) bias[nt] = b1[nt * 16 + l16];

    for (int t = gwid; t < NTILES; t += nwaves) {
        const float* zrow = z + (size_t)(t * 16 + l16) * 128;

        float4 fa[8];
#pragma unroll
        for (int kb = 0; kb < 4; kb++) {
            fa[kb * 2]     = *(const float4*)(zrow + kb * 32 + quad * 8);
            fa[kb * 2 + 1] = *(const float4*)(zrow + kb * 32 + quad * 8 + 4);
        }
        bf16x8 afrag[4];
#pragma unroll
        for (int kb = 0; kb < 4; kb++) {
            union { bf16x8 v; u32 w[4]; } pk;
            float4 lo = fa[kb * 2], hi = fa[kb * 2 + 1];
            pk.w[0] = (u32)f2bf(lo.x) | ((u32)f2bf(lo.y) << 16);
            pk.w[1] = (u32)f2bf(lo.z) | ((u32)f2bf(lo.w) << 16);
            pk.w[2] = (u32)f2bf(hi.x) | ((u32)f2bf(hi.y) << 16);
            pk.w[3] = (u32)f2bf(hi.z) | ((u32)f2bf(hi.w) << 16);
            afrag[kb] = pk.v;
        }

        f32x4 acc[8];
        const f32x4 z4 = {0.f, 0.f, 0.f, 0.f};
#pragma unroll
        for (int i = 0; i < 8; i++) acc[i] = z4;

#pragma unroll
        for (int kb = 0; kb < 4; kb++) {
            int k0 = kb * 32 + quad * 8;
#pragma unroll
            for (int nt = 0; nt < 8; nt++) {
                bf16x8 b = *(const bf16x8*)(Bs + (nt * 16 + l16) * LDK + k0);
                acc[nt] = __builtin_amdgcn_mfma_f32_16x16x32_bf16(afrag[kb], b, acc[nt], 0, 0, 0);
            }
        }

        // Epilogue: D layout col=lane&15, row=quad*4+reg; quantize to e4m3
#pragma unroll
        for (int nt = 0; nt < 8; nt++) {
            float bb = (nt < 4) ? bias[nt] : 0.f;
#pragma unroll
            for (int r = 0; r < 4; r++) {
                int row = t * 16 + quad * 4 + r;
                UVq[(size_t)row * 128 + nt * 16 + l16] = f2fp8(acc[nt][r] + bb);
            }
        }
    }
}

// ---------------------------------------------------------------------------
// Kernel 2: edge MLP, 4 lanes per edge (was 8).
// Lane c in [0,4) loads one full 16-B uint4 = the whole c-quarter of the 64-B
// U (or V) half-row. Per 4-lane group: 1 line U + 1 line V (unchanged line
// count), but each wave-level load instruction now covers 16 edges (was 8) ->
// 2x the in-flight misses at the same compiler pipelining depth.
// 64 edges/wave = 16 subs x 4 unrolled iterations.
// ---------------------------------------------------------------------------
__global__ __launch_bounds__(256) void edge_kernel(const int* __restrict__ ei,
                                                   const u8* __restrict__ UVq,
                                                   const float* __restrict__ W2,
                                                   const float* __restrict__ b2,
                                                   float* __restrict__ out) {
    int gwave = (blockIdx.x * 256 + threadIdx.x) >> 6;  // global wave id
    int lane  = threadIdx.x & 63;
    int sub   = lane >> 2;   // 0..15: edge slot within wave
    int c     = lane & 3;    // 16-fp8-col chunk id within the 64-col half

    // Per-lane W2 slice (cols c*16 .. c*16+15).
    float w2r[16];
#pragma unroll
    for (int i = 0; i < 4; i++) {
        float4 t = *(const float4*)(W2 + c * 16 + i * 4);
        w2r[i * 4 + 0] = t.x; w2r[i * 4 + 1] = t.y;
        w2r[i * 4 + 2] = t.z; w2r[i * 4 + 3] = t.w;
    }
    float b2v = b2[0];

    int ebase = gwave * 64 + sub;

#pragma unroll
    for (int it = 0; it < 4; ++it) {
        int e = ebase + it * 16;
        int s = __builtin_nontemporal_load(ei + e);
        int d = __builtin_nontemporal_load(ei + N_EDGES + e);
        uint4 a = *(const uint4*)(UVq + (size_t)s * 128 + c * 16);        // U quarter
        uint4 b = *(const uint4*)(UVq + (size_t)d * 128 + 64 + c * 16);   // V quarter
        u32 aw[4] = {a.x, a.y, a.z, a.w};
        u32 bw[4] = {b.x, b.y, b.z, b.w};
        float acc = 0.f;
#pragma unroll
        for (int i = 0; i < 4; i++) {
            // word-select must be an immediate (false=bytes 0,1; true=bytes 2,3)
            f32x2 uu0 = __builtin_amdgcn_cvt_pk_f32_fp8(aw[i], false);
            f32x2 vv0 = __builtin_amdgcn_cvt_pk_f32_fp8(bw[i], false);
            f32x2 uu1 = __builtin_amdgcn_cvt_pk_f32_fp8(aw[i], true);
            f32x2 vv1 = __builtin_amdgcn_cvt_pk_f32_fp8(bw[i], true);
            acc = fmaf(fmaxf(uu0.x + vv0.x, 0.f), w2r[i * 4 + 0], acc);
            acc = fmaf(fmaxf(uu0.y + vv0.y, 0.f), w2r[i * 4 + 1], acc);
            acc = fmaf(fmaxf(uu1.x + vv1.x, 0.f), w2r[i * 4 + 2], acc);
            acc = fmaf(fmaxf(uu1.y + vv1.y, 0.f), w2r[i * 4 + 3], acc);
        }
        // Reduce across the 4-lane group (xor 1,2 stay in-group).
        acc += __shfl_xor(acc, 1);
        acc += __shfl_xor(acc, 2);
        if (c == 0) {
            float x = acc + b2v;
            __builtin_nontemporal_store(1.f / (1.f + __expf(-x)), out + e);
        }
    }
}

// ---------------------------------------------------------------------------
extern "C" void kernel_launch(void* const* d_in, const int* in_sizes, int n_in,
                              void* d_out, int out_size, void* d_ws, size_t ws_size,
                              hipStream_t stream) {
    const float* z  = (const float*)d_in[0];
    const int*   ei = (const int*)d_in[1];   // [2][N_EDGES]
    const float* W1 = (const float*)d_in[2]; // [256][64]
    const float* b1 = (const float*)d_in[3]; // [64]
    const float* W2 = (const float*)d_in[4]; // [64][1]
    const float* b2 = (const float*)d_in[5]; // [1]
    float* out = (float*)d_out;

    u8* UVq = (u8*)d_ws;   // 12.8 MB fp8 table (prep fused into gemm)

    gemm_kernel<<<GEMM_BLOCKS, 256, 0, stream>>>(z, W1, b1, UVq);
    // 1.6M edges / (64 edges per wave) = 25000 waves = 6250 blocks of 4 waves
    edge_kernel<<<6250, 256, 0, stream>>>(ei, UVq, W2, b2, out);
}